// Round 11
// baseline (518.382 us; speedup 1.0000x reference)
//
#include <hip/hip_runtime.h>

typedef short bf16x8 __attribute__((ext_vector_type(8)));
typedef float f32x4 __attribute__((ext_vector_type(4)));
typedef float f32x16 __attribute__((ext_vector_type(16)));

#define HID   2048
#define S_LEN 2048
#define NH    16
#define HD    128
#define BATCH 2
#define NROWS (BATCH * S_LEN)  // 4096

__device__ __forceinline__ float bf2f(unsigned short u) {
    union { unsigned int i; float f; } v;
    v.i = ((unsigned int)u) << 16;
    return v.f;
}
__device__ __forceinline__ unsigned short f2bf(float f) {
    union { float f; unsigned int i; } v;
    v.f = f;
    unsigned int u = v.i;
    return (unsigned short)((u + 0x7fffu + ((u >> 16) & 1u)) >> 16);
}

// packed f32x2 -> bf16x2 (RNE). Prefer HW v_cvt_pk_bf16_f32 on gfx950.
__device__ __forceinline__ unsigned int pkbf(float a, float b) {
#if defined(__has_builtin) && __has_builtin(__builtin_amdgcn_cvt_pk_bf16_f32)
    typedef __bf16 bf2_t __attribute__((ext_vector_type(2)));
    bf2_t v = __builtin_amdgcn_cvt_pk_bf16_f32(a, b);
    unsigned int u;
    __builtin_memcpy(&u, &v, 4);
    return u;
#else
    return (unsigned int)f2bf(a) | ((unsigned int)f2bf(b) << 16);
#endif
}

__device__ __forceinline__ float exp2_fast(float x) {
#if defined(__has_builtin) && __has_builtin(__builtin_amdgcn_exp2f)
    return __builtin_amdgcn_exp2f(x);
#else
    return __expf(x * 0.6931471805599453f);
#endif
}

// async global->LDS, 16B per lane. LDS dest = wave-uniform base + lane*16B.
__device__ __forceinline__ void async16(const unsigned short* g, unsigned short* l) {
    __builtin_amdgcn_global_load_lds(
        (const __attribute__((address_space(1))) unsigned int*)g,
        (__attribute__((address_space(3))) unsigned int*)l, 16, 0, 0);
}

// ---------------- prep: z<3 -> transpose+cast W_z; z>=3 -> cast hs -> bf16 ----------------
__global__ __launch_bounds__(256) void prep(const float* __restrict__ hs,
                                            const float* __restrict__ Wa,
                                            const float* __restrict__ Wb,
                                            const float* __restrict__ Wc,
                                            unsigned short* __restrict__ Xb,
                                            unsigned short* __restrict__ WT) {
    int z = blockIdx.z;
    int t = threadIdx.x;
    if (z >= 3) {
        size_t blk = (size_t)(z - 3) * 2048 + blockIdx.y * 64 + blockIdx.x;  // 0..4095
        size_t idx = (blk * 256 + t) * 8;
        float4 v0 = *(const float4*)(hs + idx);
        float4 v1 = *(const float4*)(hs + idx + 4);
        uint4 o;
        o.x = pkbf(v0.x, v0.y);
        o.y = pkbf(v0.z, v0.w);
        o.z = pkbf(v1.x, v1.y);
        o.w = pkbf(v1.z, v1.w);
        *(uint4*)(Xb + idx) = o;
        return;
    }
    __shared__ float tile[64][33];
    int tx = t & 31, ty = t >> 5;  // 32 x 8
    int bx = blockIdx.x, by = blockIdx.y;
    const float* W = (z == 0) ? Wa : ((z == 1) ? Wb : Wc);
    unsigned short* dst = WT + (size_t)z * HID * HID;
#pragma unroll
    for (int i = 0; i < 8; i++)
        tile[ty + i * 8][tx] = W[(size_t)(by * 64 + ty + i * 8) * HID + bx * 32 + tx];
    __syncthreads();
    int k2 = tx * 2;
#pragma unroll
    for (int i = 0; i < 4; i++) {
        int j = ty + i * 8;  // 0..31
        *(unsigned int*)(dst + (size_t)(bx * 32 + j) * HID + by * 64 + k2) =
            pkbf(tile[k2][j], tile[k2 + 1][j]);
    }
}

// ---------------- standalone transpose + cast (used for Wo), vectorized ----------------
__global__ __launch_bounds__(256) void transpose_cast(const float* __restrict__ W,
                                                      unsigned short* __restrict__ WT) {
    __shared__ float tile[64][33];
    int t = threadIdx.x;
    int tx = t & 31, ty = t >> 5;
    int bx = blockIdx.x, by = blockIdx.y;   // grid (64, 32)
#pragma unroll
    for (int i = 0; i < 8; i++)
        tile[ty + i * 8][tx] = W[(size_t)(by * 64 + ty + i * 8) * HID + bx * 32 + tx];
    __syncthreads();
    int k2 = tx * 2;
#pragma unroll
    for (int i = 0; i < 4; i++) {
        int j = ty + i * 8;
        *(unsigned int*)(WT + (size_t)(bx * 32 + j) * HID + by * 64 + k2) =
            pkbf(tile[k2][j], tile[k2 + 1][j]);
    }
}

// ---------------- bf16 GEMM, BK=64 XOR-swizzled staging (proven 128^2) ----------------
// Default blockIdx mapping (r9-verified): grid.x=48 ≡ 0 mod 8 gives each XCD
// permanent ownership of 6 B-panels (L2-resident). Do NOT swizzle (r8 lesson).
template <int MODE>
__global__ __launch_bounds__(256, 2) void gemm_bt(const unsigned short* __restrict__ A,
                                                  const unsigned short* __restrict__ Bt,
                                                  unsigned short* __restrict__ Qo,
                                                  unsigned short* __restrict__ Ko,
                                                  unsigned short* __restrict__ Vo,
                                                  float* __restrict__ Fo,
                                                  const float* __restrict__ cosp,
                                                  const float* __restrict__ sinp,
                                                  int n_shift) {
    __shared__ unsigned short SM[16384];       // 32 KB: Asm(16K) + Bsm(16K); reused for rope swap
    unsigned short* Asm = SM;                  // 128 rows x 64 shorts, XOR-swizzled cols
    unsigned short* Bsm = SM + 8192;
    int t = threadIdx.x;
    int wave = t >> 6, lane = t & 63;
    int wm = wave >> 1, wn = wave & 1;
    int c = lane & 15, quad = lane >> 4;
    int m0 = blockIdx.y * 128, nloc = blockIdx.x * 128;

    int lr = lane >> 3;
    int cb = (lane & 7) ^ (lr & 7);
    const unsigned short* Ag = A + (size_t)(m0 + wave * 32 + lr) * HID + cb * 8;
    const unsigned short* Bg = Bt + (size_t)(nloc + wave * 32 + lr) * HID + cb * 8;
    unsigned short* Al = Asm + wave * 2048;  // 32 rows * 64 shorts
    unsigned short* Bl = Bsm + wave * 2048;

    f32x4 zero = {0.f, 0.f, 0.f, 0.f};
    f32x4 acc[4][4];
#pragma unroll
    for (int i = 0; i < 4; i++)
#pragma unroll
        for (int j = 0; j < 4; j++) acc[i][j] = zero;

    for (int it = 0; it < 32; it++) {
        int k0 = it * 64;
#pragma unroll
        for (int j = 0; j < 4; j++) {
            async16(Ag + k0 + j * 8 * HID, Al + j * 512);
            async16(Bg + k0 + j * 8 * HID, Bl + j * 512);
        }
        __syncthreads();
#pragma unroll
        for (int kk = 0; kk < 2; kk++) {
            bf16x8 af[4], bfr[4];
#pragma unroll
            for (int mt = 0; mt < 4; mt++)
                af[mt] = *(const bf16x8*)(Asm + (wm * 64 + mt * 16 + c) * 64 +
                                          (((kk * 4 + quad) ^ (c & 7)) * 8));
#pragma unroll
            for (int nt = 0; nt < 4; nt++)
                bfr[nt] = *(const bf16x8*)(Bsm + (wn * 64 + nt * 16 + c) * 64 +
                                           (((kk * 4 + quad) ^ (c & 7)) * 8));
#pragma unroll
            for (int mt = 0; mt < 4; mt++)
#pragma unroll
                for (int nt = 0; nt < 4; nt++)
                    acc[mt][nt] = __builtin_amdgcn_mfma_f32_16x16x32_bf16(af[mt], bfr[nt],
                                                                          acc[mt][nt], 0, 0, 0);
        }
        __syncthreads();
    }

    if (MODE == 2) {
#pragma unroll
        for (int mt = 0; mt < 4; mt++)
#pragma unroll
            for (int nt = 0; nt < 4; nt++)
#pragma unroll
                for (int r = 0; r < 4; r++) {
                    int row = m0 + wm * 64 + mt * 16 + quad * 4 + r;
                    int col = nloc + wn * 64 + nt * 16 + c;
                    Fo[(size_t)row * HID + col] = acc[mt][nt][r];
                }
    } else {
        int nglob0 = n_shift + nloc;
        int mat = nglob0 >> 11;         // block-uniform
        int h = (nglob0 & 2047) >> 7;   // block covers exactly one head (128 cols)
        if (mat == 2) {
#pragma unroll
            for (int mt = 0; mt < 4; mt++)
#pragma unroll
                for (int nt = 0; nt < 4; nt++) {
                    int d = wn * 64 + nt * 16 + c;
                    int row0 = m0 + wm * 64 + mt * 16 + quad * 4;
                    int b = row0 >> 11, s = row0 & 2047;
                    ushort4 o;
                    o.x = f2bf(acc[mt][nt][0]);
                    o.y = f2bf(acc[mt][nt][1]);
                    o.z = f2bf(acc[mt][nt][2]);
                    o.w = f2bf(acc[mt][nt][3]);
                    *(ushort4*)(Vo + ((size_t)(b * NH + h) * HD + d) * S_LEN + s) = o;
                }
        } else {
            unsigned short* Cb = (mat == 0) ? Qo : Ko;
            float scl = (mat == 0) ? 0.12751743f : 1.0f;  // log2(e)/sqrt(128) folded into Q
            __syncthreads();
#pragma unroll
            for (int mt = 0; mt < 4; mt++)
#pragma unroll
                for (int nt = 0; nt < 4; nt++) {
                    ushort4 o;
                    o.x = f2bf(acc[mt][nt][0]);
                    o.y = f2bf(acc[mt][nt][1]);
                    o.z = f2bf(acc[mt][nt][2]);
                    o.w = f2bf(acc[mt][nt][3]);
                    *(ushort4*)(SM + (mt * 4 + nt) * 1024 + t * 4) = o;
                }
            __syncthreads();
            int partner = (wm * 2 + (wn ^ 1)) * 64 + lane;
            float sgn = wn ? 1.0f : -1.0f;
#pragma unroll
            for (int mt = 0; mt < 4; mt++) {
#pragma unroll
                for (int nt = 0; nt < 4; nt++) {
                    ushort4 pv = *(const ushort4*)(SM + (mt * 4 + nt) * 1024 + partner * 4);
                    float part[4] = {bf2f(pv.x), bf2f(pv.y), bf2f(pv.z), bf2f(pv.w)};
                    int col = wn * 64 + nt * 16 + c;
#pragma unroll
                    for (int r = 0; r < 4; r++) {
                        int row = m0 + wm * 64 + mt * 16 + quad * 4 + r;
                        int b = row >> 11, s = row & 2047;
                        float cv = cosp[s * HD + col], sv = sinp[s * HD + col];
                        float out = (acc[mt][nt][r] * cv + sgn * part[r] * sv) * scl;
                        Cb[((size_t)(b * NH + h) * S_LEN + s) * HD + col] = f2bf(out);
                    }
                }
            }
        }
    }
}

// ---------------- flash attention, 32x32 swapped-MFMA, in-register P (T12) ----------------
// r10 structure (verified): QK^T as mfma_32x32x16(K,Q); P -> PV A-operand via
// 16 cvt_pk + 8 permlane32_swap, no Psm, no per-iter lgkmcnt(0). Staging +
// vmcnt ledger identical to r7 (verified): K dbuf, V single, issue V(i+1),
// K(i+2) at iter end; vmcnt(8)@B0 drains K(i), vmcnt(4)@B1 drains V(i).
// r11: __launch_bounds__(256,3) -> 3 blocks/CU (LDS 3x48=144<=160 KB, VGPR
// cap ~168). +50% resident waves to hide K/V L2/L3 latency (attn is
// latency/BW-bound on the staging path; LDS-op count no longer dominant).
__global__ __launch_bounds__(256, 3) void attn_kernel(const unsigned short* __restrict__ Q,
                                                      const unsigned short* __restrict__ Kg,
                                                      const unsigned short* __restrict__ Vt,
                                                      unsigned short* __restrict__ Aout) {
    __shared__ unsigned short Ksm[2 * 64 * 128];        // 32 KB dbuf, [key][d], XOR-16 chunks
    __shared__ unsigned short Vsm[128 * 64];            // 16 KB, [d][key], XOR-8 chunks
    int bh = blockIdx.y;
    int b = bh >> 4, h = bh & 15;
    int t = threadIdx.x;
    int wave = t >> 6, lane = t & 63;
    int w31 = lane & 31, hi = lane >> 5;
    int q0 = blockIdx.x * 128 + wave * 32;
    const unsigned short* Qp = Q + (size_t)bh * S_LEN * HD;
    const unsigned short* Kp = Kg + (size_t)bh * S_LEN * HD;
    const unsigned short* Vp = Vt + (size_t)bh * HD * S_LEN;

    // persistent Q fragments (B-operand): B[k=d][col=qrow]: lane holds
    // Q[q0+w31][kb*16 + hi*8 + j] — 8 k-blocks cover d=128.
    bf16x8 qf[8];
#pragma unroll
    for (int kb = 0; kb < 8; kb++)
        qf[kb] = *(const bf16x8*)(Qp + (size_t)(q0 + w31) * HD + kb * 16 + hi * 8);

    f32x16 o_acc[4];
#pragma unroll
    for (int dt = 0; dt < 4; dt++)
#pragma unroll
        for (int r = 0; r < 16; r++) o_acc[dt][r] = 0.f;
    float lsum = 0.f;

#define STAGE_K(CH, BUF) {                                                      \
    _Pragma("unroll")                                                           \
    for (int j = 0; j < 4; j++) {                                               \
        int fc = (wave * 4 + j) * 64 + lane;                                    \
        int rK = fc >> 4, cbK = (fc & 15) ^ (rK & 15);                          \
        async16(Kp + (size_t)((CH) * 64 + rK) * HD + cbK * 8,                   \
                Ksm + (BUF) * 8192 + (wave * 4 + j) * 512); } }
#define STAGE_V(CH) {                                                           \
    _Pragma("unroll")                                                           \
    for (int j = 0; j < 4; j++) {                                               \
        int fc = (wave * 4 + j) * 64 + lane;                                    \
        int rV = fc >> 3, cbV = (fc & 7) ^ (rV & 7);                            \
        async16(Vp + (size_t)rV * S_LEN + (CH) * 64 + cbV * 8,                  \
                Vsm + (wave * 4 + j) * 512); } }

// softmax+pack for one 32x32 S^T tile (keys kt*32 + (r&3)+8*(r>>2)+4*hi):
// A-operand word w holds keys ks*16 + hi*8 + {2w,2w+1}; one permlane32_swap
// fills two words (exchanges this reg's hi-half with partner reg's lo-half).
#define SM_PACK(S, PA0, PA1) {                                                  \
    float e_[16];                                                               \
    _Pragma("unroll")                                                           \
    for (int r_ = 0; r_ < 16; r_++) { e_[r_] = exp2_fast((S)[r_]); lsum += e_[r_]; } \
    unsigned int a0_ = pkbf(e_[0], e_[1]),  b0_ = pkbf(e_[4], e_[5]);           \
    unsigned int a1_ = pkbf(e_[2], e_[3]),  b1_ = pkbf(e_[6], e_[7]);           \
    asm volatile("v_permlane32_swap_b32 %0, %1" : "+v"(a0_), "+v"(b0_));        \
    asm volatile("v_permlane32_swap_b32 %0, %1" : "+v"(a1_), "+v"(b1_));        \
    { uint4 w_ = {a0_, a1_, b0_, b1_}; __builtin_memcpy(&PA0, &w_, 16); }       \
    unsigned int c0_ = pkbf(e_[8], e_[9]),   d0_ = pkbf(e_[12], e_[13]);        \
    unsigned int c1_ = pkbf(e_[10], e_[11]), d1_ = pkbf(e_[14], e_[15]);        \
    asm volatile("v_permlane32_swap_b32 %0, %1" : "+v"(c0_), "+v"(d0_));        \
    asm volatile("v_permlane32_swap_b32 %0, %1" : "+v"(c1_), "+v"(d1_));        \
    { uint4 w_ = {c0_, c1_, d0_, d1_}; __builtin_memcpy(&PA1, &w_, 16); } }

    // prologue: ledger-consistent with steady state (qf loads drain at i=0 B0)
    STAGE_K(0, 0);
    STAGE_V(0);
    STAGE_K(1, 1);

    for (int i = 0; i < 32; i++) {
        const unsigned short* Kb = Ksm + (i & 1) * 8192;
        __builtin_amdgcn_s_waitcnt(0x0F78);  // vmcnt(8): K(i) landed (+Q on i==0)
        __builtin_amdgcn_s_barrier();        // B0
        __builtin_amdgcn_sched_barrier(0);

        // S^T = K * Q^T : two 32-key tiles, 8 d-slices of 16
        f32x16 s0, s1;
#pragma unroll
        for (int r = 0; r < 16; r++) { s0[r] = 0.f; s1[r] = 0.f; }
        __builtin_amdgcn_s_setprio(1);
#pragma unroll
        for (int kb = 0; kb < 8; kb++) {
            int ch = ((kb * 2 + hi) ^ (w31 & 15)) * 8;
            bf16x8 k0 = *(const bf16x8*)(Kb + (size_t)w31 * 128 + ch);
            bf16x8 k1 = *(const bf16x8*)(Kb + (size_t)(32 + w31) * 128 + ch);
            s0 = __builtin_amdgcn_mfma_f32_32x32x16_bf16(k0, qf[kb], s0, 0, 0, 0);
            s1 = __builtin_amdgcn_mfma_f32_32x32x16_bf16(k1, qf[kb], s1, 0, 0, 0);
        }
        __builtin_amdgcn_s_setprio(0);

        // softmax (no-max, scale pre-folded) + in-register P pack
        bf16x8 pa[4];
        SM_PACK(s0, pa[0], pa[1]);
        SM_PACK(s1, pa[2], pa[3]);

        __builtin_amdgcn_sched_barrier(0);
        __builtin_amdgcn_s_waitcnt(0x0F74);  // vmcnt(4): V(i) landed; K(i+1) in flight
        __builtin_amdgcn_s_barrier();        // B1
        __builtin_amdgcn_sched_barrier(0);

        // O += P * V : A = pa[ks] (qrow x key16), B = Vsm[d][key] slices
        __builtin_amdgcn_s_setprio(1);
#pragma unroll
        for (int dt = 0; dt < 4; dt++) {
#pragma unroll
            for (int ks = 0; ks < 4; ks++) {
                bf16x8 vf = *(const bf16x8*)(Vsm + (size_t)(dt * 32 + w31) * 64 +
                                             (((ks * 2 + hi) ^ (w31 & 7)) * 8));
                o_acc[dt] = __builtin_amdgcn_mfma_f32_32x32x16_bf16(pa[ks], vf,
                                                                    o_acc[dt], 0, 0, 0);
            }
        }
        __builtin_amdgcn_s_setprio(0);
        __builtin_amdgcn_sched_barrier(0);
        __builtin_amdgcn_s_barrier();        // B2: all Vsm/Kbuf reads complete
        __builtin_amdgcn_sched_barrier(0);

        // stage next chunks (ledger order: V first, then K)
        int nv = (i + 1 > 31) ? 31 : i + 1;
        int nk = (i + 2 > 31) ? 31 : i + 2;
        STAGE_V(nv);
        STAGE_K(nk, (i & 1));
    }
#undef STAGE_K
#undef STAGE_V
#undef SM_PACK

    // lsum: lane l holds partial over its 32 keys; partner (l^32) has the rest.
    lsum += __shfl_xor(lsum, 32);
    float invv = 1.0f / lsum;           // lane l&31 == qrow holds inv[qrow]
    float inv[16];
#pragma unroll
    for (int r = 0; r < 16; r++)
        inv[r] = __shfl(invv, (r & 3) + 8 * (r >> 2) + 4 * hi);

#pragma unroll
    for (int dt = 0; dt < 4; dt++) {
#pragma unroll
        for (int r = 0; r < 16; r++) {
            int srow = q0 + (r & 3) + 8 * (r >> 2) + 4 * hi;
            Aout[((size_t)(b * S_LEN + srow)) * HID + h * HD + dt * 32 + w31] =
                f2bf(o_acc[dt][r] * inv[r]);
        }
    }
}

extern "C" void kernel_launch(void* const* d_in, const int* in_sizes, int n_in,
                              void* d_out, int out_size, void* d_ws, size_t ws_size,
                              hipStream_t stream) {
    const float* hs   = (const float*)d_in[0];
    const float* cosp = (const float*)d_in[1];
    const float* sinp = (const float*)d_in[2];
    const float* Wq   = (const float*)d_in[3];
    const float* Wk   = (const float*)d_in[4];
    const float* Wv   = (const float*)d_in[5];
    const float* Wo   = (const float*)d_in[6];

    char* ws = (char*)d_ws;
    unsigned short* Xb = (unsigned short*)(ws);                      // 0-16 MB (reused as Aout)
    unsigned short* Qb = (unsigned short*)(ws + (16ull << 20));      // 16-32
    unsigned short* Kb = (unsigned short*)(ws + (32ull << 20));      // 32-48
    unsigned short* Vb = (unsigned short*)(ws + (48ull << 20));      // 48-64
    unsigned short* WT = (unsigned short*)(ws + (64ull << 20));      // 64-88 fused / 64-72 single

    const bool fused = ws_size >= (88ull << 20);

    if (fused) {
        // 1. cast + 3 weight transposes in one launch (vectorized writes)
        prep<<<dim3(64, 32, 5), 256, 0, stream>>>(hs, Wq, Wk, Wv, Xb, WT);
        // 2. fused QKV GEMM with RoPE epilogue (proven r0 kernel, default mapping)
        gemm_bt<0><<<dim3(48, 32), 256, 0, stream>>>(Xb, WT, Qb, Kb, Vb, nullptr,
                                                     cosp, sinp, 0);
        // 3. flash attention (32x32 swapped MFMA, in-register P, 3 blocks/CU)
        attn_kernel<<<dim3(16, 32), 256, 0, stream>>>(Qb, Kb, Vb, Xb /*Aout*/);
        // 4. Wo transpose into dead Qb region
        unsigned short* WoT = (unsigned short*)(ws + (16ull << 20));
        transpose_cast<<<dim3(64, 32), 256, 0, stream>>>(Wo, WoT);
        // 5. output GEMM, fp32 direct to d_out
        gemm_bt<2><<<dim3(16, 32), 256, 0, stream>>>(Xb, WoT, nullptr, nullptr, nullptr,
                                                     (float*)d_out, cosp, sinp, 0);
    } else {
        prep<<<dim3(64, 32, 5), 256, 0, stream>>>(hs, Wq, Wq, Wq, Xb, WT);  // cast + Wq^T
        gemm_bt<0><<<dim3(16, 32), 256, 0, stream>>>(Xb, WT, Qb, Kb, Vb, nullptr,
                                                     cosp, sinp, 0);
        transpose_cast<<<dim3(64, 32), 256, 0, stream>>>(Wk, WT);
        gemm_bt<0><<<dim3(16, 32), 256, 0, stream>>>(Xb, WT, Qb, Kb, Vb, nullptr,
                                                     cosp, sinp, 2048);
        transpose_cast<<<dim3(64, 32), 256, 0, stream>>>(Wv, WT);
        gemm_bt<0><<<dim3(16, 32), 256, 0, stream>>>(Xb, WT, Qb, Kb, Vb, nullptr,
                                                     cosp, sinp, 4096);
        attn_kernel<<<dim3(16, 32), 256, 0, stream>>>(Qb, Kb, Vb, Xb /*Aout*/);
        transpose_cast<<<dim3(64, 32), 256, 0, stream>>>(Wo, WT);
        gemm_bt<2><<<dim3(16, 32), 256, 0, stream>>>(Xb, WT, nullptr, nullptr, nullptr,
                                                     (float*)d_out, cosp, sinp, 0);
    }
}

// Round 12
// 390.736 us; speedup vs baseline: 1.3267x; 1.3267x over previous
//
#include <hip/hip_runtime.h>

typedef short bf16x8 __attribute__((ext_vector_type(8)));
typedef float f32x4 __attribute__((ext_vector_type(4)));
typedef float f32x16 __attribute__((ext_vector_type(16)));

#define HID   2048
#define S_LEN 2048
#define NH    16
#define HD    128
#define BATCH 2
#define NROWS (BATCH * S_LEN)  // 4096

__device__ __forceinline__ float bf2f(unsigned short u) {
    union { unsigned int i; float f; } v;
    v.i = ((unsigned int)u) << 16;
    return v.f;
}
__device__ __forceinline__ unsigned short f2bf(float f) {
    union { float f; unsigned int i; } v;
    v.f = f;
    unsigned int u = v.i;
    return (unsigned short)((u + 0x7fffu + ((u >> 16) & 1u)) >> 16);
}

// packed f32x2 -> bf16x2 (RNE). Prefer HW v_cvt_pk_bf16_f32 on gfx950.
__device__ __forceinline__ unsigned int pkbf(float a, float b) {
#if defined(__has_builtin) && __has_builtin(__builtin_amdgcn_cvt_pk_bf16_f32)
    typedef __bf16 bf2_t __attribute__((ext_vector_type(2)));
    bf2_t v = __builtin_amdgcn_cvt_pk_bf16_f32(a, b);
    unsigned int u;
    __builtin_memcpy(&u, &v, 4);
    return u;
#else
    return (unsigned int)f2bf(a) | ((unsigned int)f2bf(b) << 16);
#endif
}

__device__ __forceinline__ float exp2_fast(float x) {
#if defined(__has_builtin) && __has_builtin(__builtin_amdgcn_exp2f)
    return __builtin_amdgcn_exp2f(x);
#else
    return __expf(x * 0.6931471805599453f);
#endif
}

// async global->LDS, 16B per lane. LDS dest = wave-uniform base + lane*16B.
__device__ __forceinline__ void async16(const unsigned short* g, unsigned short* l) {
    __builtin_amdgcn_global_load_lds(
        (const __attribute__((address_space(1))) unsigned int*)g,
        (__attribute__((address_space(3))) unsigned int*)l, 16, 0, 0);
}

// ---------------- prep: z<3 -> transpose+cast W_z; z>=3 -> cast hs -> bf16 ----------------
__global__ __launch_bounds__(256) void prep(const float* __restrict__ hs,
                                            const float* __restrict__ Wa,
                                            const float* __restrict__ Wb,
                                            const float* __restrict__ Wc,
                                            unsigned short* __restrict__ Xb,
                                            unsigned short* __restrict__ WT) {
    int z = blockIdx.z;
    int t = threadIdx.x;
    if (z >= 3) {
        size_t blk = (size_t)(z - 3) * 2048 + blockIdx.y * 64 + blockIdx.x;  // 0..4095
        size_t idx = (blk * 256 + t) * 8;
        float4 v0 = *(const float4*)(hs + idx);
        float4 v1 = *(const float4*)(hs + idx + 4);
        uint4 o;
        o.x = pkbf(v0.x, v0.y);
        o.y = pkbf(v0.z, v0.w);
        o.z = pkbf(v1.x, v1.y);
        o.w = pkbf(v1.z, v1.w);
        *(uint4*)(Xb + idx) = o;
        return;
    }
    __shared__ float tile[64][33];
    int tx = t & 31, ty = t >> 5;  // 32 x 8
    int bx = blockIdx.x, by = blockIdx.y;
    const float* W = (z == 0) ? Wa : ((z == 1) ? Wb : Wc);
    unsigned short* dst = WT + (size_t)z * HID * HID;
#pragma unroll
    for (int i = 0; i < 8; i++)
        tile[ty + i * 8][tx] = W[(size_t)(by * 64 + ty + i * 8) * HID + bx * 32 + tx];
    __syncthreads();
    int k2 = tx * 2;
#pragma unroll
    for (int i = 0; i < 4; i++) {
        int j = ty + i * 8;  // 0..31
        *(unsigned int*)(dst + (size_t)(bx * 32 + j) * HID + by * 64 + k2) =
            pkbf(tile[k2][j], tile[k2 + 1][j]);
    }
}

// ---------------- standalone transpose + cast (used for Wo), vectorized ----------------
__global__ __launch_bounds__(256) void transpose_cast(const float* __restrict__ W,
                                                      unsigned short* __restrict__ WT) {
    __shared__ float tile[64][33];
    int t = threadIdx.x;
    int tx = t & 31, ty = t >> 5;
    int bx = blockIdx.x, by = blockIdx.y;   // grid (64, 32)
#pragma unroll
    for (int i = 0; i < 8; i++)
        tile[ty + i * 8][tx] = W[(size_t)(by * 64 + ty + i * 8) * HID + bx * 32 + tx];
    __syncthreads();
    int k2 = tx * 2;
#pragma unroll
    for (int i = 0; i < 4; i++) {
        int j = ty + i * 8;
        *(unsigned int*)(WT + (size_t)(bx * 32 + j) * HID + by * 64 + k2) =
            pkbf(tile[k2][j], tile[k2 + 1][j]);
    }
}

// ---------------- bf16 GEMM, BK=64 XOR-swizzled staging (proven 128^2) ----------------
// Default blockIdx mapping (r9-verified): grid.x=48 ≡ 0 mod 8 gives each XCD
// permanent ownership of 6 B-panels (L2-resident). Do NOT swizzle (r8 lesson).
template <int MODE>
__global__ __launch_bounds__(256, 2) void gemm_bt(const unsigned short* __restrict__ A,
                                                  const unsigned short* __restrict__ Bt,
                                                  unsigned short* __restrict__ Qo,
                                                  unsigned short* __restrict__ Ko,
                                                  unsigned short* __restrict__ Vo,
                                                  float* __restrict__ Fo,
                                                  const float* __restrict__ cosp,
                                                  const float* __restrict__ sinp,
                                                  int n_shift) {
    __shared__ unsigned short SM[16384];       // 32 KB: Asm(16K) + Bsm(16K); reused for rope swap
    unsigned short* Asm = SM;                  // 128 rows x 64 shorts, XOR-swizzled cols
    unsigned short* Bsm = SM + 8192;
    int t = threadIdx.x;
    int wave = t >> 6, lane = t & 63;
    int wm = wave >> 1, wn = wave & 1;
    int c = lane & 15, quad = lane >> 4;
    int m0 = blockIdx.y * 128, nloc = blockIdx.x * 128;

    int lr = lane >> 3;
    int cb = (lane & 7) ^ (lr & 7);
    const unsigned short* Ag = A + (size_t)(m0 + wave * 32 + lr) * HID + cb * 8;
    const unsigned short* Bg = Bt + (size_t)(nloc + wave * 32 + lr) * HID + cb * 8;
    unsigned short* Al = Asm + wave * 2048;  // 32 rows * 64 shorts
    unsigned short* Bl = Bsm + wave * 2048;

    f32x4 zero = {0.f, 0.f, 0.f, 0.f};
    f32x4 acc[4][4];
#pragma unroll
    for (int i = 0; i < 4; i++)
#pragma unroll
        for (int j = 0; j < 4; j++) acc[i][j] = zero;

    for (int it = 0; it < 32; it++) {
        int k0 = it * 64;
#pragma unroll
        for (int j = 0; j < 4; j++) {
            async16(Ag + k0 + j * 8 * HID, Al + j * 512);
            async16(Bg + k0 + j * 8 * HID, Bl + j * 512);
        }
        __syncthreads();
#pragma unroll
        for (int kk = 0; kk < 2; kk++) {
            bf16x8 af[4], bfr[4];
#pragma unroll
            for (int mt = 0; mt < 4; mt++)
                af[mt] = *(const bf16x8*)(Asm + (wm * 64 + mt * 16 + c) * 64 +
                                          (((kk * 4 + quad) ^ (c & 7)) * 8));
#pragma unroll
            for (int nt = 0; nt < 4; nt++)
                bfr[nt] = *(const bf16x8*)(Bsm + (wn * 64 + nt * 16 + c) * 64 +
                                           (((kk * 4 + quad) ^ (c & 7)) * 8));
#pragma unroll
            for (int mt = 0; mt < 4; mt++)
#pragma unroll
                for (int nt = 0; nt < 4; nt++)
                    acc[mt][nt] = __builtin_amdgcn_mfma_f32_16x16x32_bf16(af[mt], bfr[nt],
                                                                          acc[mt][nt], 0, 0, 0);
        }
        __syncthreads();
    }

    if (MODE == 2) {
#pragma unroll
        for (int mt = 0; mt < 4; mt++)
#pragma unroll
            for (int nt = 0; nt < 4; nt++)
#pragma unroll
                for (int r = 0; r < 4; r++) {
                    int row = m0 + wm * 64 + mt * 16 + quad * 4 + r;
                    int col = nloc + wn * 64 + nt * 16 + c;
                    Fo[(size_t)row * HID + col] = acc[mt][nt][r];
                }
    } else {
        int nglob0 = n_shift + nloc;
        int mat = nglob0 >> 11;         // block-uniform
        int h = (nglob0 & 2047) >> 7;   // block covers exactly one head (128 cols)
        if (mat == 2) {
#pragma unroll
            for (int mt = 0; mt < 4; mt++)
#pragma unroll
                for (int nt = 0; nt < 4; nt++) {
                    int d = wn * 64 + nt * 16 + c;
                    int row0 = m0 + wm * 64 + mt * 16 + quad * 4;
                    int b = row0 >> 11, s = row0 & 2047;
                    ushort4 o;
                    o.x = f2bf(acc[mt][nt][0]);
                    o.y = f2bf(acc[mt][nt][1]);
                    o.z = f2bf(acc[mt][nt][2]);
                    o.w = f2bf(acc[mt][nt][3]);
                    *(ushort4*)(Vo + ((size_t)(b * NH + h) * HD + d) * S_LEN + s) = o;
                }
        } else {
            unsigned short* Cb = (mat == 0) ? Qo : Ko;
            float scl = (mat == 0) ? 0.12751743f : 1.0f;  // log2(e)/sqrt(128) folded into Q
            __syncthreads();
#pragma unroll
            for (int mt = 0; mt < 4; mt++)
#pragma unroll
                for (int nt = 0; nt < 4; nt++) {
                    ushort4 o;
                    o.x = f2bf(acc[mt][nt][0]);
                    o.y = f2bf(acc[mt][nt][1]);
                    o.z = f2bf(acc[mt][nt][2]);
                    o.w = f2bf(acc[mt][nt][3]);
                    *(ushort4*)(SM + (mt * 4 + nt) * 1024 + t * 4) = o;
                }
            __syncthreads();
            int partner = (wm * 2 + (wn ^ 1)) * 64 + lane;
            float sgn = wn ? 1.0f : -1.0f;
#pragma unroll
            for (int mt = 0; mt < 4; mt++) {
#pragma unroll
                for (int nt = 0; nt < 4; nt++) {
                    ushort4 pv = *(const ushort4*)(SM + (mt * 4 + nt) * 1024 + partner * 4);
                    float part[4] = {bf2f(pv.x), bf2f(pv.y), bf2f(pv.z), bf2f(pv.w)};
                    int col = wn * 64 + nt * 16 + c;
#pragma unroll
                    for (int r = 0; r < 4; r++) {
                        int row = m0 + wm * 64 + mt * 16 + quad * 4 + r;
                        int b = row >> 11, s = row & 2047;
                        float cv = cosp[s * HD + col], sv = sinp[s * HD + col];
                        float out = (acc[mt][nt][r] * cv + sgn * part[r] * sv) * scl;
                        Cb[((size_t)(b * NH + h) * S_LEN + s) * HD + col] = f2bf(out);
                    }
                }
            }
        }
    }
}

// ---------------- flash attention, 32x32 swapped-MFMA, in-register P (T12) ----------------
// r10 structure (verified, 2 blocks/CU — r11's (256,3) spilled to 84 VGPR and
// regressed 2.4x; REVERTED). r12: bijective XCD-chunked grid remap.
// Default dispatch spreads the 16 q-blocks of each (b,h) over all 8 XCDs ->
// every XCD fetches that head's 1 MB K/V (measured FETCH 342 MB ≈ 8x KV + Q).
// Remap wg=(bid&7)*64+(bid>>3), qb=wg&15, bh=wg>>4: XCD x owns bh in
// [4x,4x+4) with ALL q-blocks -> per-XCD KV working set 4 MB (= L2), KV hits
// HBM once. Block-bijection => correctness-invariant.
__global__ __launch_bounds__(256, 2) void attn_kernel(const unsigned short* __restrict__ Q,
                                                      const unsigned short* __restrict__ Kg,
                                                      const unsigned short* __restrict__ Vt,
                                                      unsigned short* __restrict__ Aout) {
    __shared__ unsigned short Ksm[2 * 64 * 128];        // 32 KB dbuf, [key][d], XOR-16 chunks
    __shared__ unsigned short Vsm[128 * 64];            // 16 KB, [d][key], XOR-8 chunks
    int bid = blockIdx.y * 16 + blockIdx.x;             // grid (16, 32) -> 512 blocks
    int wg = (bid & 7) * 64 + (bid >> 3);               // bijective (512 % 8 == 0)
    int qb = wg & 15, bh = wg >> 4;
    int b = bh >> 4, h = bh & 15;
    int t = threadIdx.x;
    int wave = t >> 6, lane = t & 63;
    int w31 = lane & 31, hi = lane >> 5;
    int q0 = qb * 128 + wave * 32;
    const unsigned short* Qp = Q + (size_t)bh * S_LEN * HD;
    const unsigned short* Kp = Kg + (size_t)bh * S_LEN * HD;
    const unsigned short* Vp = Vt + (size_t)bh * HD * S_LEN;

    // persistent Q fragments (B-operand): B[k=d][col=qrow]: lane holds
    // Q[q0+w31][kb*16 + hi*8 + j] — 8 k-blocks cover d=128.
    bf16x8 qf[8];
#pragma unroll
    for (int kb = 0; kb < 8; kb++)
        qf[kb] = *(const bf16x8*)(Qp + (size_t)(q0 + w31) * HD + kb * 16 + hi * 8);

    f32x16 o_acc[4];
#pragma unroll
    for (int dt = 0; dt < 4; dt++)
#pragma unroll
        for (int r = 0; r < 16; r++) o_acc[dt][r] = 0.f;
    float lsum = 0.f;

#define STAGE_K(CH, BUF) {                                                      \
    _Pragma("unroll")                                                           \
    for (int j = 0; j < 4; j++) {                                               \
        int fc = (wave * 4 + j) * 64 + lane;                                    \
        int rK = fc >> 4, cbK = (fc & 15) ^ (rK & 15);                          \
        async16(Kp + (size_t)((CH) * 64 + rK) * HD + cbK * 8,                   \
                Ksm + (BUF) * 8192 + (wave * 4 + j) * 512); } }
#define STAGE_V(CH) {                                                           \
    _Pragma("unroll")                                                           \
    for (int j = 0; j < 4; j++) {                                               \
        int fc = (wave * 4 + j) * 64 + lane;                                    \
        int rV = fc >> 3, cbV = (fc & 7) ^ (rV & 7);                            \
        async16(Vp + (size_t)rV * S_LEN + (CH) * 64 + cbV * 8,                  \
                Vsm + (wave * 4 + j) * 512); } }

// softmax+pack for one 32x32 S^T tile (keys kt*32 + (r&3)+8*(r>>2)+4*hi):
// A-operand word w holds keys ks*16 + hi*8 + {2w,2w+1}; one permlane32_swap
// fills two words (exchanges this reg's hi-half with partner reg's lo-half).
#define SM_PACK(S, PA0, PA1) {                                                  \
    float e_[16];                                                               \
    _Pragma("unroll")                                                           \
    for (int r_ = 0; r_ < 16; r_++) { e_[r_] = exp2_fast((S)[r_]); lsum += e_[r_]; } \
    unsigned int a0_ = pkbf(e_[0], e_[1]),  b0_ = pkbf(e_[4], e_[5]);           \
    unsigned int a1_ = pkbf(e_[2], e_[3]),  b1_ = pkbf(e_[6], e_[7]);           \
    asm volatile("v_permlane32_swap_b32 %0, %1" : "+v"(a0_), "+v"(b0_));        \
    asm volatile("v_permlane32_swap_b32 %0, %1" : "+v"(a1_), "+v"(b1_));        \
    { uint4 w_ = {a0_, a1_, b0_, b1_}; __builtin_memcpy(&PA0, &w_, 16); }       \
    unsigned int c0_ = pkbf(e_[8], e_[9]),   d0_ = pkbf(e_[12], e_[13]);        \
    unsigned int c1_ = pkbf(e_[10], e_[11]), d1_ = pkbf(e_[14], e_[15]);        \
    asm volatile("v_permlane32_swap_b32 %0, %1" : "+v"(c0_), "+v"(d0_));        \
    asm volatile("v_permlane32_swap_b32 %0, %1" : "+v"(c1_), "+v"(d1_));        \
    { uint4 w_ = {c0_, c1_, d0_, d1_}; __builtin_memcpy(&PA1, &w_, 16); } }

    // prologue: ledger-consistent with steady state (qf loads drain at i=0 B0)
    STAGE_K(0, 0);
    STAGE_V(0);
    STAGE_K(1, 1);

    for (int i = 0; i < 32; i++) {
        const unsigned short* Kb = Ksm + (i & 1) * 8192;
        __builtin_amdgcn_s_waitcnt(0x0F78);  // vmcnt(8): K(i) landed (+Q on i==0)
        __builtin_amdgcn_s_barrier();        // B0
        __builtin_amdgcn_sched_barrier(0);

        // S^T = K * Q^T : two 32-key tiles, 8 d-slices of 16
        f32x16 s0, s1;
#pragma unroll
        for (int r = 0; r < 16; r++) { s0[r] = 0.f; s1[r] = 0.f; }
        __builtin_amdgcn_s_setprio(1);
#pragma unroll
        for (int kb = 0; kb < 8; kb++) {
            int ch = ((kb * 2 + hi) ^ (w31 & 15)) * 8;
            bf16x8 k0 = *(const bf16x8*)(Kb + (size_t)w31 * 128 + ch);
            bf16x8 k1 = *(const bf16x8*)(Kb + (size_t)(32 + w31) * 128 + ch);
            s0 = __builtin_amdgcn_mfma_f32_32x32x16_bf16(k0, qf[kb], s0, 0, 0, 0);
            s1 = __builtin_amdgcn_mfma_f32_32x32x16_bf16(k1, qf[kb], s1, 0, 0, 0);
        }
        __builtin_amdgcn_s_setprio(0);

        // softmax (no-max, scale pre-folded) + in-register P pack
        bf16x8 pa[4];
        SM_PACK(s0, pa[0], pa[1]);
        SM_PACK(s1, pa[2], pa[3]);

        __builtin_amdgcn_sched_barrier(0);
        __builtin_amdgcn_s_waitcnt(0x0F74);  // vmcnt(4): V(i) landed; K(i+1) in flight
        __builtin_amdgcn_s_barrier();        // B1
        __builtin_amdgcn_sched_barrier(0);

        // O += P * V : A = pa[ks] (qrow x key16), B = Vsm[d][key] slices
        __builtin_amdgcn_s_setprio(1);
#pragma unroll
        for (int dt = 0; dt < 4; dt++) {
#pragma unroll
            for (int ks = 0; ks < 4; ks++) {
                bf16x8 vf = *(const bf16x8*)(Vsm + (size_t)(dt * 32 + w31) * 64 +
                                             (((ks * 2 + hi) ^ (w31 & 7)) * 8));
                o_acc[dt] = __builtin_amdgcn_mfma_f32_32x32x16_bf16(pa[ks], vf,
                                                                    o_acc[dt], 0, 0, 0);
            }
        }
        __builtin_amdgcn_s_setprio(0);
        __builtin_amdgcn_sched_barrier(0);
        __builtin_amdgcn_s_barrier();        // B2: all Vsm/Kbuf reads complete
        __builtin_amdgcn_sched_barrier(0);

        // stage next chunks (ledger order: V first, then K)
        int nv = (i + 1 > 31) ? 31 : i + 1;
        int nk = (i + 2 > 31) ? 31 : i + 2;
        STAGE_V(nv);
        STAGE_K(nk, (i & 1));
    }
#undef STAGE_K
#undef STAGE_V
#undef SM_PACK

    // lsum: lane l holds partial over its 32 keys; partner (l^32) has the rest.
    lsum += __shfl_xor(lsum, 32);
    float invv = 1.0f / lsum;           // lane l&31 == qrow holds inv[qrow]
    float inv[16];
#pragma unroll
    for (int r = 0; r < 16; r++)
        inv[r] = __shfl(invv, (r & 3) + 8 * (r >> 2) + 4 * hi);

#pragma unroll
    for (int dt = 0; dt < 4; dt++) {
#pragma unroll
        for (int r = 0; r < 16; r++) {
            int srow = q0 + (r & 3) + 8 * (r >> 2) + 4 * hi;
            Aout[((size_t)(b * S_LEN + srow)) * HID + h * HD + dt * 32 + w31] =
                f2bf(o_acc[dt][r] * inv[r]);
        }
    }
}

extern "C" void kernel_launch(void* const* d_in, const int* in_sizes, int n_in,
                              void* d_out, int out_size, void* d_ws, size_t ws_size,
                              hipStream_t stream) {
    const float* hs   = (const float*)d_in[0];
    const float* cosp = (const float*)d_in[1];
    const float* sinp = (const float*)d_in[2];
    const float* Wq   = (const float*)d_in[3];
    const float* Wk   = (const float*)d_in[4];
    const float* Wv   = (const float*)d_in[5];
    const float* Wo   = (const float*)d_in[6];

    char* ws = (char*)d_ws;
    unsigned short* Xb = (unsigned short*)(ws);                      // 0-16 MB (reused as Aout)
    unsigned short* Qb = (unsigned short*)(ws + (16ull << 20));      // 16-32
    unsigned short* Kb = (unsigned short*)(ws + (32ull << 20));      // 32-48
    unsigned short* Vb = (unsigned short*)(ws + (48ull << 20));      // 48-64
    unsigned short* WT = (unsigned short*)(ws + (64ull << 20));      // 64-88 fused / 64-72 single

    const bool fused = ws_size >= (88ull << 20);

    if (fused) {
        // 1. cast + 3 weight transposes in one launch (vectorized writes)
        prep<<<dim3(64, 32, 5), 256, 0, stream>>>(hs, Wq, Wk, Wv, Xb, WT);
        // 2. fused QKV GEMM with RoPE epilogue (proven r0 kernel, default mapping)
        gemm_bt<0><<<dim3(48, 32), 256, 0, stream>>>(Xb, WT, Qb, Kb, Vb, nullptr,
                                                     cosp, sinp, 0);
        // 3. flash attention (32x32 swapped MFMA, in-register P, XCD-owned heads)
        attn_kernel<<<dim3(16, 32), 256, 0, stream>>>(Qb, Kb, Vb, Xb /*Aout*/);
        // 4. Wo transpose into dead Qb region
        unsigned short* WoT = (unsigned short*)(ws + (16ull << 20));
        transpose_cast<<<dim3(64, 32), 256, 0, stream>>>(Wo, WoT);
        // 5. output GEMM, fp32 direct to d_out
        gemm_bt<2><<<dim3(16, 32), 256, 0, stream>>>(Xb, WoT, nullptr, nullptr, nullptr,
                                                     (float*)d_out, cosp, sinp, 0);
    } else {
        prep<<<dim3(64, 32, 5), 256, 0, stream>>>(hs, Wq, Wq, Wq, Xb, WT);  // cast + Wq^T
        gemm_bt<0><<<dim3(16, 32), 256, 0, stream>>>(Xb, WT, Qb, Kb, Vb, nullptr,
                                                     cosp, sinp, 0);
        transpose_cast<<<dim3(64, 32), 256, 0, stream>>>(Wk, WT);
        gemm_bt<0><<<dim3(16, 32), 256, 0, stream>>>(Xb, WT, Qb, Kb, Vb, nullptr,
                                                     cosp, sinp, 2048);
        transpose_cast<<<dim3(64, 32), 256, 0, stream>>>(Wv, WT);
        gemm_bt<0><<<dim3(16, 32), 256, 0, stream>>>(Xb, WT, Qb, Kb, Vb, nullptr,
                                                     cosp, sinp, 4096);
        attn_kernel<<<dim3(16, 32), 256, 0, stream>>>(Qb, Kb, Vb, Xb /*Aout*/);
        transpose_cast<<<dim3(64, 32), 256, 0, stream>>>(Wo, WT);
        gemm_bt<2><<<dim3(16, 32), 256, 0, stream>>>(Xb, WT, nullptr, nullptr, nullptr,
                                                     (float*)d_out, cosp, sinp, 0);
    }
}

// Round 13
// 373.180 us; speedup vs baseline: 1.3891x; 1.0470x over previous
//
#include <hip/hip_runtime.h>

typedef short bf16x8 __attribute__((ext_vector_type(8)));
typedef float f32x4 __attribute__((ext_vector_type(4)));
typedef float f32x16 __attribute__((ext_vector_type(16)));

#define HID   2048
#define S_LEN 2048
#define NH    16
#define HD    128
#define BATCH 2
#define NROWS (BATCH * S_LEN)  // 4096

__device__ __forceinline__ float bf2f(unsigned short u) {
    union { unsigned int i; float f; } v;
    v.i = ((unsigned int)u) << 16;
    return v.f;
}
__device__ __forceinline__ unsigned short f2bf(float f) {
    union { float f; unsigned int i; } v;
    v.f = f;
    unsigned int u = v.i;
    return (unsigned short)((u + 0x7fffu + ((u >> 16) & 1u)) >> 16);
}

// packed f32x2 -> bf16x2 (RNE). Prefer HW v_cvt_pk_bf16_f32 on gfx950.
__device__ __forceinline__ unsigned int pkbf(float a, float b) {
#if defined(__has_builtin) && __has_builtin(__builtin_amdgcn_cvt_pk_bf16_f32)
    typedef __bf16 bf2_t __attribute__((ext_vector_type(2)));
    bf2_t v = __builtin_amdgcn_cvt_pk_bf16_f32(a, b);
    unsigned int u;
    __builtin_memcpy(&u, &v, 4);
    return u;
#else
    return (unsigned int)f2bf(a) | ((unsigned int)f2bf(b) << 16);
#endif
}

__device__ __forceinline__ float exp2_fast(float x) {
#if defined(__has_builtin) && __has_builtin(__builtin_amdgcn_exp2f)
    return __builtin_amdgcn_exp2f(x);
#else
    return __expf(x * 0.6931471805599453f);
#endif
}

// async global->LDS, 16B per lane. LDS dest = wave-uniform base + lane*16B.
__device__ __forceinline__ void async16(const unsigned short* g, unsigned short* l) {
    __builtin_amdgcn_global_load_lds(
        (const __attribute__((address_space(1))) unsigned int*)g,
        (__attribute__((address_space(3))) unsigned int*)l, 16, 0, 0);
}

// ---------------- prep: z<3 -> transpose+cast W_z; z>=3 -> cast hs -> bf16 ----------------
__global__ __launch_bounds__(256) void prep(const float* __restrict__ hs,
                                            const float* __restrict__ Wa,
                                            const float* __restrict__ Wb,
                                            const float* __restrict__ Wc,
                                            unsigned short* __restrict__ Xb,
                                            unsigned short* __restrict__ WT) {
    int z = blockIdx.z;
    int t = threadIdx.x;
    if (z >= 3) {
        size_t blk = (size_t)(z - 3) * 2048 + blockIdx.y * 64 + blockIdx.x;  // 0..4095
        size_t idx = (blk * 256 + t) * 8;
        float4 v0 = *(const float4*)(hs + idx);
        float4 v1 = *(const float4*)(hs + idx + 4);
        uint4 o;
        o.x = pkbf(v0.x, v0.y);
        o.y = pkbf(v0.z, v0.w);
        o.z = pkbf(v1.x, v1.y);
        o.w = pkbf(v1.z, v1.w);
        *(uint4*)(Xb + idx) = o;
        return;
    }
    __shared__ float tile[64][33];
    int tx = t & 31, ty = t >> 5;  // 32 x 8
    int bx = blockIdx.x, by = blockIdx.y;
    const float* W = (z == 0) ? Wa : ((z == 1) ? Wb : Wc);
    unsigned short* dst = WT + (size_t)z * HID * HID;
#pragma unroll
    for (int i = 0; i < 8; i++)
        tile[ty + i * 8][tx] = W[(size_t)(by * 64 + ty + i * 8) * HID + bx * 32 + tx];
    __syncthreads();
    int k2 = tx * 2;
#pragma unroll
    for (int i = 0; i < 4; i++) {
        int j = ty + i * 8;  // 0..31
        *(unsigned int*)(dst + (size_t)(bx * 32 + j) * HID + by * 64 + k2) =
            pkbf(tile[k2][j], tile[k2 + 1][j]);
    }
}

// ---------------- standalone transpose + cast (used for Wo), vectorized ----------------
__global__ __launch_bounds__(256) void transpose_cast(const float* __restrict__ W,
                                                      unsigned short* __restrict__ WT) {
    __shared__ float tile[64][33];
    int t = threadIdx.x;
    int tx = t & 31, ty = t >> 5;
    int bx = blockIdx.x, by = blockIdx.y;   // grid (64, 32)
#pragma unroll
    for (int i = 0; i < 8; i++)
        tile[ty + i * 8][tx] = W[(size_t)(by * 64 + ty + i * 8) * HID + bx * 32 + tx];
    __syncthreads();
    int k2 = tx * 2;
#pragma unroll
    for (int i = 0; i < 4; i++) {
        int j = ty + i * 8;
        *(unsigned int*)(WT + (size_t)(bx * 32 + j) * HID + by * 64 + k2) =
            pkbf(tile[k2][j], tile[k2 + 1][j]);
    }
}

// ---------------- bf16 GEMM, BK=64 XOR-swizzled staging (proven 128^2) ----------------
// Default blockIdx mapping (r9-verified): grid.x=48 ≡ 0 mod 8 gives each XCD
// permanent ownership of 6 B-panels (L2-resident). Do NOT swizzle (r8 lesson).
template <int MODE>
__global__ __launch_bounds__(256, 2) void gemm_bt(const unsigned short* __restrict__ A,
                                                  const unsigned short* __restrict__ Bt,
                                                  unsigned short* __restrict__ Qo,
                                                  unsigned short* __restrict__ Ko,
                                                  unsigned short* __restrict__ Vo,
                                                  float* __restrict__ Fo,
                                                  const float* __restrict__ cosp,
                                                  const float* __restrict__ sinp,
                                                  int n_shift) {
    __shared__ unsigned short SM[16384];       // 32 KB: Asm(16K) + Bsm(16K); reused for rope swap
    unsigned short* Asm = SM;                  // 128 rows x 64 shorts, XOR-swizzled cols
    unsigned short* Bsm = SM + 8192;
    int t = threadIdx.x;
    int wave = t >> 6, lane = t & 63;
    int wm = wave >> 1, wn = wave & 1;
    int c = lane & 15, quad = lane >> 4;
    int m0 = blockIdx.y * 128, nloc = blockIdx.x * 128;

    int lr = lane >> 3;
    int cb = (lane & 7) ^ (lr & 7);
    const unsigned short* Ag = A + (size_t)(m0 + wave * 32 + lr) * HID + cb * 8;
    const unsigned short* Bg = Bt + (size_t)(nloc + wave * 32 + lr) * HID + cb * 8;
    unsigned short* Al = Asm + wave * 2048;  // 32 rows * 64 shorts
    unsigned short* Bl = Bsm + wave * 2048;

    f32x4 zero = {0.f, 0.f, 0.f, 0.f};
    f32x4 acc[4][4];
#pragma unroll
    for (int i = 0; i < 4; i++)
#pragma unroll
        for (int j = 0; j < 4; j++) acc[i][j] = zero;

    for (int it = 0; it < 32; it++) {
        int k0 = it * 64;
#pragma unroll
        for (int j = 0; j < 4; j++) {
            async16(Ag + k0 + j * 8 * HID, Al + j * 512);
            async16(Bg + k0 + j * 8 * HID, Bl + j * 512);
        }
        __syncthreads();
#pragma unroll
        for (int kk = 0; kk < 2; kk++) {
            bf16x8 af[4], bfr[4];
#pragma unroll
            for (int mt = 0; mt < 4; mt++)
                af[mt] = *(const bf16x8*)(Asm + (wm * 64 + mt * 16 + c) * 64 +
                                          (((kk * 4 + quad) ^ (c & 7)) * 8));
#pragma unroll
            for (int nt = 0; nt < 4; nt++)
                bfr[nt] = *(const bf16x8*)(Bsm + (wn * 64 + nt * 16 + c) * 64 +
                                           (((kk * 4 + quad) ^ (c & 7)) * 8));
#pragma unroll
            for (int mt = 0; mt < 4; mt++)
#pragma unroll
                for (int nt = 0; nt < 4; nt++)
                    acc[mt][nt] = __builtin_amdgcn_mfma_f32_16x16x32_bf16(af[mt], bfr[nt],
                                                                          acc[mt][nt], 0, 0, 0);
        }
        __syncthreads();
    }

    if (MODE == 2) {
#pragma unroll
        for (int mt = 0; mt < 4; mt++)
#pragma unroll
            for (int nt = 0; nt < 4; nt++)
#pragma unroll
                for (int r = 0; r < 4; r++) {
                    int row = m0 + wm * 64 + mt * 16 + quad * 4 + r;
                    int col = nloc + wn * 64 + nt * 16 + c;
                    Fo[(size_t)row * HID + col] = acc[mt][nt][r];
                }
    } else {
        int nglob0 = n_shift + nloc;
        int mat = nglob0 >> 11;         // block-uniform
        int h = (nglob0 & 2047) >> 7;   // block covers exactly one head (128 cols)
        if (mat == 2) {
#pragma unroll
            for (int mt = 0; mt < 4; mt++)
#pragma unroll
                for (int nt = 0; nt < 4; nt++) {
                    int d = wn * 64 + nt * 16 + c;
                    int row0 = m0 + wm * 64 + mt * 16 + quad * 4;
                    int b = row0 >> 11, s = row0 & 2047;
                    ushort4 o;
                    o.x = f2bf(acc[mt][nt][0]);
                    o.y = f2bf(acc[mt][nt][1]);
                    o.z = f2bf(acc[mt][nt][2]);
                    o.w = f2bf(acc[mt][nt][3]);
                    *(ushort4*)(Vo + ((size_t)(b * NH + h) * HD + d) * S_LEN + s) = o;
                }
        } else {
            unsigned short* Cb = (mat == 0) ? Qo : Ko;
            float scl = (mat == 0) ? 0.12751743f : 1.0f;  // log2(e)/sqrt(128) folded into Q
            __syncthreads();
#pragma unroll
            for (int mt = 0; mt < 4; mt++)
#pragma unroll
                for (int nt = 0; nt < 4; nt++) {
                    ushort4 o;
                    o.x = f2bf(acc[mt][nt][0]);
                    o.y = f2bf(acc[mt][nt][1]);
                    o.z = f2bf(acc[mt][nt][2]);
                    o.w = f2bf(acc[mt][nt][3]);
                    *(ushort4*)(SM + (mt * 4 + nt) * 1024 + t * 4) = o;
                }
            __syncthreads();
            int partner = (wm * 2 + (wn ^ 1)) * 64 + lane;
            float sgn = wn ? 1.0f : -1.0f;
#pragma unroll
            for (int mt = 0; mt < 4; mt++) {
#pragma unroll
                for (int nt = 0; nt < 4; nt++) {
                    ushort4 pv = *(const ushort4*)(SM + (mt * 4 + nt) * 1024 + partner * 4);
                    float part[4] = {bf2f(pv.x), bf2f(pv.y), bf2f(pv.z), bf2f(pv.w)};
                    int col = wn * 64 + nt * 16 + c;
#pragma unroll
                    for (int r = 0; r < 4; r++) {
                        int row = m0 + wm * 64 + mt * 16 + quad * 4 + r;
                        int b = row >> 11, s = row & 2047;
                        float cv = cosp[s * HD + col], sv = sinp[s * HD + col];
                        float out = (acc[mt][nt][r] * cv + sgn * part[r] * sv) * scl;
                        Cb[((size_t)(b * NH + h) * S_LEN + s) * HD + col] = f2bf(out);
                    }
                }
            }
        }
    }
}

// ---------------- flash attention, 32x32 swapped-MFMA, in-register P (T12) ----------------
// r10 configuration (session best, 385.3 us): QK^T as mfma_32x32x16(K,Q);
// P -> PV A-operand via 16 cvt_pk + 8 permlane32_swap, no Psm, no per-iter
// lgkmcnt(0). Staging + vmcnt ledger (r7-verified): K dbuf, V single, issue
// V(i+1),K(i+2) at iter end; vmcnt(8)@B0 drains K(i), vmcnt(4)@B1 drains V(i).
// Default block mapping (r12's XCD remap: neutral within noise). 2 blocks/CU
// (r11's (256,3): spilled to 84 VGPR, 2.4x regression — do not raise).
__global__ __launch_bounds__(256, 2) void attn_kernel(const unsigned short* __restrict__ Q,
                                                      const unsigned short* __restrict__ Kg,
                                                      const unsigned short* __restrict__ Vt,
                                                      unsigned short* __restrict__ Aout) {
    __shared__ unsigned short Ksm[2 * 64 * 128];        // 32 KB dbuf, [key][d], XOR-16 chunks
    __shared__ unsigned short Vsm[128 * 64];            // 16 KB, [d][key], XOR-8 chunks
    int bh = blockIdx.y;
    int b = bh >> 4, h = bh & 15;
    int t = threadIdx.x;
    int wave = t >> 6, lane = t & 63;
    int w31 = lane & 31, hi = lane >> 5;
    int q0 = blockIdx.x * 128 + wave * 32;
    const unsigned short* Qp = Q + (size_t)bh * S_LEN * HD;
    const unsigned short* Kp = Kg + (size_t)bh * S_LEN * HD;
    const unsigned short* Vp = Vt + (size_t)bh * HD * S_LEN;

    // persistent Q fragments (B-operand): B[k=d][col=qrow]: lane holds
    // Q[q0+w31][kb*16 + hi*8 + j] — 8 k-blocks cover d=128.
    bf16x8 qf[8];
#pragma unroll
    for (int kb = 0; kb < 8; kb++)
        qf[kb] = *(const bf16x8*)(Qp + (size_t)(q0 + w31) * HD + kb * 16 + hi * 8);

    f32x16 o_acc[4];
#pragma unroll
    for (int dt = 0; dt < 4; dt++)
#pragma unroll
        for (int r = 0; r < 16; r++) o_acc[dt][r] = 0.f;
    float lsum = 0.f;

#define STAGE_K(CH, BUF) {                                                      \
    _Pragma("unroll")                                                           \
    for (int j = 0; j < 4; j++) {                                               \
        int fc = (wave * 4 + j) * 64 + lane;                                    \
        int rK = fc >> 4, cbK = (fc & 15) ^ (rK & 15);                          \
        async16(Kp + (size_t)((CH) * 64 + rK) * HD + cbK * 8,                   \
                Ksm + (BUF) * 8192 + (wave * 4 + j) * 512); } }
#define STAGE_V(CH) {                                                           \
    _Pragma("unroll")                                                           \
    for (int j = 0; j < 4; j++) {                                               \
        int fc = (wave * 4 + j) * 64 + lane;                                    \
        int rV = fc >> 3, cbV = (fc & 7) ^ (rV & 7);                            \
        async16(Vp + (size_t)rV * S_LEN + (CH) * 64 + cbV * 8,                  \
                Vsm + (wave * 4 + j) * 512); } }

// softmax+pack for one 32x32 S^T tile (keys kt*32 + (r&3)+8*(r>>2)+4*hi):
// A-operand word w holds keys ks*16 + hi*8 + {2w,2w+1}; one permlane32_swap
// fills two words (exchanges this reg's hi-half with partner reg's lo-half).
#define SM_PACK(S, PA0, PA1) {                                                  \
    float e_[16];                                                               \
    _Pragma("unroll")                                                           \
    for (int r_ = 0; r_ < 16; r_++) { e_[r_] = exp2_fast((S)[r_]); lsum += e_[r_]; } \
    unsigned int a0_ = pkbf(e_[0], e_[1]),  b0_ = pkbf(e_[4], e_[5]);           \
    unsigned int a1_ = pkbf(e_[2], e_[3]),  b1_ = pkbf(e_[6], e_[7]);           \
    asm volatile("v_permlane32_swap_b32 %0, %1" : "+v"(a0_), "+v"(b0_));        \
    asm volatile("v_permlane32_swap_b32 %0, %1" : "+v"(a1_), "+v"(b1_));        \
    { uint4 w_ = {a0_, a1_, b0_, b1_}; __builtin_memcpy(&PA0, &w_, 16); }       \
    unsigned int c0_ = pkbf(e_[8], e_[9]),   d0_ = pkbf(e_[12], e_[13]);        \
    unsigned int c1_ = pkbf(e_[10], e_[11]), d1_ = pkbf(e_[14], e_[15]);        \
    asm volatile("v_permlane32_swap_b32 %0, %1" : "+v"(c0_), "+v"(d0_));        \
    asm volatile("v_permlane32_swap_b32 %0, %1" : "+v"(c1_), "+v"(d1_));        \
    { uint4 w_ = {c0_, c1_, d0_, d1_}; __builtin_memcpy(&PA1, &w_, 16); } }

    // prologue: ledger-consistent with steady state (qf loads drain at i=0 B0)
    STAGE_K(0, 0);
    STAGE_V(0);
    STAGE_K(1, 1);

    for (int i = 0; i < 32; i++) {
        const unsigned short* Kb = Ksm + (i & 1) * 8192;
        __builtin_amdgcn_s_waitcnt(0x0F78);  // vmcnt(8): K(i) landed (+Q on i==0)
        __builtin_amdgcn_s_barrier();        // B0
        __builtin_amdgcn_sched_barrier(0);

        // S^T = K * Q^T : two 32-key tiles, 8 d-slices of 16
        f32x16 s0, s1;
#pragma unroll
        for (int r = 0; r < 16; r++) { s0[r] = 0.f; s1[r] = 0.f; }
        __builtin_amdgcn_s_setprio(1);
#pragma unroll
        for (int kb = 0; kb < 8; kb++) {
            int ch = ((kb * 2 + hi) ^ (w31 & 15)) * 8;
            bf16x8 k0 = *(const bf16x8*)(Kb + (size_t)w31 * 128 + ch);
            bf16x8 k1 = *(const bf16x8*)(Kb + (size_t)(32 + w31) * 128 + ch);
            s0 = __builtin_amdgcn_mfma_f32_32x32x16_bf16(k0, qf[kb], s0, 0, 0, 0);
            s1 = __builtin_amdgcn_mfma_f32_32x32x16_bf16(k1, qf[kb], s1, 0, 0, 0);
        }
        __builtin_amdgcn_s_setprio(0);

        // softmax (no-max, scale pre-folded) + in-register P pack
        bf16x8 pa[4];
        SM_PACK(s0, pa[0], pa[1]);
        SM_PACK(s1, pa[2], pa[3]);

        __builtin_amdgcn_sched_barrier(0);
        __builtin_amdgcn_s_waitcnt(0x0F74);  // vmcnt(4): V(i) landed; K(i+1) in flight
        __builtin_amdgcn_s_barrier();        // B1
        __builtin_amdgcn_sched_barrier(0);

        // O += P * V : A = pa[ks] (qrow x key16), B = Vsm[d][key] slices
        __builtin_amdgcn_s_setprio(1);
#pragma unroll
        for (int dt = 0; dt < 4; dt++) {
#pragma unroll
            for (int ks = 0; ks < 4; ks++) {
                bf16x8 vf = *(const bf16x8*)(Vsm + (size_t)(dt * 32 + w31) * 64 +
                                             (((ks * 2 + hi) ^ (w31 & 7)) * 8));
                o_acc[dt] = __builtin_amdgcn_mfma_f32_32x32x16_bf16(pa[ks], vf,
                                                                    o_acc[dt], 0, 0, 0);
            }
        }
        __builtin_amdgcn_s_setprio(0);
        __builtin_amdgcn_sched_barrier(0);
        __builtin_amdgcn_s_barrier();        // B2: all Vsm/Kbuf reads complete
        __builtin_amdgcn_sched_barrier(0);

        // stage next chunks (ledger order: V first, then K)
        int nv = (i + 1 > 31) ? 31 : i + 1;
        int nk = (i + 2 > 31) ? 31 : i + 2;
        STAGE_V(nv);
        STAGE_K(nk, (i & 1));
    }
#undef STAGE_K
#undef STAGE_V
#undef SM_PACK

    // lsum: lane l holds partial over its 32 keys; partner (l^32) has the rest.
    lsum += __shfl_xor(lsum, 32);
    float invv = 1.0f / lsum;           // lane l&31 == qrow holds inv[qrow]
    float inv[16];
#pragma unroll
    for (int r = 0; r < 16; r++)
        inv[r] = __shfl(invv, (r & 3) + 8 * (r >> 2) + 4 * hi);

#pragma unroll
    for (int dt = 0; dt < 4; dt++) {
#pragma unroll
        for (int r = 0; r < 16; r++) {
            int srow = q0 + (r & 3) + 8 * (r >> 2) + 4 * hi;
            Aout[((size_t)(b * S_LEN + srow)) * HID + h * HD + dt * 32 + w31] =
                f2bf(o_acc[dt][r] * inv[r]);
        }
    }
}

extern "C" void kernel_launch(void* const* d_in, const int* in_sizes, int n_in,
                              void* d_out, int out_size, void* d_ws, size_t ws_size,
                              hipStream_t stream) {
    const float* hs   = (const float*)d_in[0];
    const float* cosp = (const float*)d_in[1];
    const float* sinp = (const float*)d_in[2];
    const float* Wq   = (const float*)d_in[3];
    const float* Wk   = (const float*)d_in[4];
    const float* Wv   = (const float*)d_in[5];
    const float* Wo   = (const float*)d_in[6];

    char* ws = (char*)d_ws;
    unsigned short* Xb = (unsigned short*)(ws);                      // 0-16 MB (reused as Aout)
    unsigned short* Qb = (unsigned short*)(ws + (16ull << 20));      // 16-32
    unsigned short* Kb = (unsigned short*)(ws + (32ull << 20));      // 32-48
    unsigned short* Vb = (unsigned short*)(ws + (48ull << 20));      // 48-64
    unsigned short* WT = (unsigned short*)(ws + (64ull << 20));      // 64-88 fused / 64-72 single

    const bool fused = ws_size >= (88ull << 20);

    if (fused) {
        // 1. cast + 3 weight transposes in one launch (vectorized writes)
        prep<<<dim3(64, 32, 5), 256, 0, stream>>>(hs, Wq, Wk, Wv, Xb, WT);
        // 2. fused QKV GEMM with RoPE epilogue (proven r0 kernel, default mapping)
        gemm_bt<0><<<dim3(48, 32), 256, 0, stream>>>(Xb, WT, Qb, Kb, Vb, nullptr,
                                                     cosp, sinp, 0);
        // 3. flash attention (32x32 swapped MFMA, in-register P)
        attn_kernel<<<dim3(16, 32), 256, 0, stream>>>(Qb, Kb, Vb, Xb /*Aout*/);
        // 4. Wo transpose into dead Qb region
        unsigned short* WoT = (unsigned short*)(ws + (16ull << 20));
        transpose_cast<<<dim3(64, 32), 256, 0, stream>>>(Wo, WoT);
        // 5. output GEMM, fp32 direct to d_out
        gemm_bt<2><<<dim3(16, 32), 256, 0, stream>>>(Xb, WoT, nullptr, nullptr, nullptr,
                                                     (float*)d_out, cosp, sinp, 0);
    } else {
        prep<<<dim3(64, 32, 5), 256, 0, stream>>>(hs, Wq, Wq, Wq, Xb, WT);  // cast + Wq^T
        gemm_bt<0><<<dim3(16, 32), 256, 0, stream>>>(Xb, WT, Qb, Kb, Vb, nullptr,
                                                     cosp, sinp, 0);
        transpose_cast<<<dim3(64, 32), 256, 0, stream>>>(Wk, WT);
        gemm_bt<0><<<dim3(16, 32), 256, 0, stream>>>(Xb, WT, Qb, Kb, Vb, nullptr,
                                                     cosp, sinp, 2048);
        transpose_cast<<<dim3(64, 32), 256, 0, stream>>>(Wv, WT);
        gemm_bt<0><<<dim3(16, 32), 256, 0, stream>>>(Xb, WT, Qb, Kb, Vb, nullptr,
                                                     cosp, sinp, 4096);
        attn_kernel<<<dim3(16, 32), 256, 0, stream>>>(Qb, Kb, Vb, Xb /*Aout*/);
        transpose_cast<<<dim3(64, 32), 256, 0, stream>>>(Wo, WT);
        gemm_bt<2><<<dim3(16, 32), 256, 0, stream>>>(Xb, WT, nullptr, nullptr, nullptr,
                                                     (float*)d_out, cosp, sinp, 0);
    }
}